// Round 6
// baseline (121.649 us; speedup 1.0000x reference)
//
#include <hip/hip_runtime.h>
#include <hip/hip_bf16.h>

#define EMBED 512
#define NSEQ 2048
#define NROWS 4096

typedef unsigned short u16;
typedef __bf16 bf16x8 __attribute__((ext_vector_type(8)));
typedef float f32x4 __attribute__((ext_vector_type(4)));
typedef unsigned short ushort8 __attribute__((ext_vector_type(8)));

__device__ __forceinline__ u16 f2bf(float f) {
    unsigned u = __float_as_uint(f);
    unsigned r = (u + 0x7FFFu + ((u >> 16) & 1u)) >> 16;
    return (u16)r;
}
__device__ __forceinline__ float bf2f(u16 v) {
    return __uint_as_float((unsigned)v << 16);
}

#define XELEMS    (NROWS * EMBED)     // 2097152
#define WQKELEMS  (1024 * EMBED)      // 524288

// ---------------------------------------------------------------------------
// prep: blocks 0..1023:  x -> bf16, R0-style one-shot streaming (8 elem/thr).
//       blocks 1024..1279: Wq|Wk -> Wcat bf16, one-shot.
//       blocks 1280..1343: colsum partials of x (fp32), 64-row chunks,
//                          pure streaming ILP — no LDS, no barrier.
// xcs_part layout: [b*32+chunk][512] f32 (128 KB total).
// ---------------------------------------------------------------------------
__global__ __launch_bounds__(256) void prep_kernel(
    const float* __restrict__ x,
    const float* __restrict__ Wq, const float* __restrict__ Wk,
    u16* __restrict__ xb, u16* __restrict__ Wcat,
    float* __restrict__ xcs_part)
{
    const int bid = blockIdx.x, t = threadIdx.x;
    if (bid < 1280) {
        const float* src;
        u16* dst;
        if (bid < 1024) {
            const long long e0 = (long long)bid * 2048 + (long long)t * 8;
            src = x + e0; dst = xb + e0;
        } else {
            const long long j = (long long)(bid - 1024) * 2048 + (long long)t * 8;
            const int row = (int)(j >> 9), col = (int)(j & 511);
            src = (row < 512) ? (Wq + (size_t)row * EMBED + col)
                              : (Wk + (size_t)(row - 512) * EMBED + col);
            dst = Wcat + j;
        }
        float4 a = *(const float4*)(src);
        float4 b = *(const float4*)(src + 4);
        union { u16 u[8]; uint4 v; } p;
        p.u[0]=f2bf(a.x); p.u[1]=f2bf(a.y); p.u[2]=f2bf(a.z); p.u[3]=f2bf(a.w);
        p.u[4]=f2bf(b.x); p.u[5]=f2bf(b.y); p.u[6]=f2bf(b.z); p.u[7]=f2bf(b.w);
        *(uint4*)(dst) = p.v;
    } else {
        // colsum partial: 64-row chunk, thread t owns cols 2t, 2t+1
        const int cid   = bid - 1280;            // 0..63
        const int b     = cid >> 5;              // batch
        const int chunk = cid & 31;              // 32 chunks of 64 rows
        const float* p = x + ((size_t)b * NSEQ + (size_t)chunk * 64) * EMBED + 2 * t;
        float a0 = 0.f, a1 = 0.f, c0 = 0.f, c1 = 0.f;
#pragma unroll 8
        for (int rr = 0; rr < 64; rr += 2) {
            float2 u = *(const float2*)(p + (size_t)rr * EMBED);
            float2 v = *(const float2*)(p + (size_t)(rr + 1) * EMBED);
            a0 += u.x; a1 += u.y; c0 += v.x; c1 += v.y;
        }
        float2 o = make_float2(a0 + c0, a1 + c1);
        *(float2*)(xcs_part + ((size_t)(b * 32 + chunk) * 512) + 2 * t) = o;
    }
}

// ---------------------------------------------------------------------------
// vsmall: 32 blocks = (batch, head, j-half). Reduce xcs partials, compute the
// 4 V-vectors (rows 0..2 + tail = colsumV - (v0+v1+v2)), fold with Wo -> WT.
// ---------------------------------------------------------------------------
__global__ __launch_bounds__(256) void vsmall_kernel(
    const u16* __restrict__ xb, const float* __restrict__ xcs_part,
    const float* __restrict__ bv, const float* __restrict__ Wv,
    const float* __restrict__ Wo, float* __restrict__ WT)
{
    __shared__ float xcs[512];
    __shared__ float Vraw[4][64];
    __shared__ float Vloc[4][64];
    const int t = threadIdx.x;
    const int sid = blockIdx.x;                // 0..31
    const int b = sid >> 4, h = (sid >> 1) & 7, jhalf = sid & 1;

    // 1) xcs[d] = sum over 32 chunk partials (fp32, deterministic)
    {
        const float* p = xcs_part + (size_t)b * 32 * 512 + 2 * t;
        float a0 = 0.f, a1 = 0.f, c0 = 0.f, c1 = 0.f;
#pragma unroll
        for (int ch = 0; ch < 32; ch += 2) {
            float2 u = *(const float2*)(p + (size_t)ch * 512);
            float2 v = *(const float2*)(p + (size_t)(ch + 1) * 512);
            a0 += u.x; a1 += u.y; c0 += v.x; c1 += v.y;
        }
        xcs[2 * t] = a0 + c0; xcs[2 * t + 1] = a1 + c1;
    }
    __syncthreads();

    // 2) raw V dots: wave tt<3 -> x row tt of batch; wave 3 -> colsum row
    const int tt = t >> 6, cl = t & 63;
    const int col = h * 64 + cl;
    const float* wv = Wv + (size_t)col * EMBED;
    float r = 0.f;
    if (tt < 3) {
        const u16* xr = xb + ((size_t)b * NSEQ + tt) * EMBED;
#pragma unroll 8
        for (int d = 0; d < EMBED; d += 8) {
            ushort8 xv = *(const ushort8*)(xr + d);
            f32x4 w0 = *(const f32x4*)(wv + d);
            f32x4 w1 = *(const f32x4*)(wv + d + 4);
            r = fmaf(bf2f(xv[0]), w0[0], r);
            r = fmaf(bf2f(xv[1]), w0[1], r);
            r = fmaf(bf2f(xv[2]), w0[2], r);
            r = fmaf(bf2f(xv[3]), w0[3], r);
            r = fmaf(bf2f(xv[4]), w1[0], r);
            r = fmaf(bf2f(xv[5]), w1[1], r);
            r = fmaf(bf2f(xv[6]), w1[2], r);
            r = fmaf(bf2f(xv[7]), w1[3], r);
        }
    } else {
#pragma unroll 8
        for (int d = 0; d < EMBED; d += 4) {
            f32x4 w = *(const f32x4*)(wv + d);
            r = fmaf(xcs[d],     w[0], r);
            r = fmaf(xcs[d + 1], w[1], r);
            r = fmaf(xcs[d + 2], w[2], r);
            r = fmaf(xcs[d + 3], w[3], r);
        }
    }
    Vraw[tt][cl] = r;
    __syncthreads();
    // biased rows; tail = colsumV - (v0+v1+v2) = r3 - (r0+r1+r2) + 2045*bv
    const float bvc = bv[col];
    if (tt < 3) Vloc[tt][cl] = r + bvc;
    else        Vloc[3][cl] = r - (Vraw[0][cl] + Vraw[1][cl] + Vraw[2][cl])
                                + 2045.f * bvc;
    __syncthreads();

    // 3) WT[b][j][4h+t] = sum_{c in head h} Vloc[t][c] * Wo[j][c]
    const int j = jhalf * 256 + t;
    const float* wo = Wo + (size_t)j * EMBED + h * 64;
    float a0 = 0.f, a1 = 0.f, a2 = 0.f, a3 = 0.f;
#pragma unroll
    for (int c = 0; c < 64; c += 4) {
        f32x4 w = *(const f32x4*)(wo + c);
#pragma unroll
        for (int z = 0; z < 4; ++z) {
            a0 = fmaf(Vloc[0][c + z], w[z], a0);
            a1 = fmaf(Vloc[1][c + z], w[z], a1);
            a2 = fmaf(Vloc[2][c + z], w[z], a2);
            a3 = fmaf(Vloc[3][c + z], w[z], a3);
        }
    }
    float* wt = WT + ((size_t)b * 512 + j) * 32 + h * 4;
    wt[0] = a0; wt[1] = a1; wt[2] = a2; wt[3] = a3;
}

// ---------------------------------------------------------------------------
// Q|K GEMM: 512 blocks, R0's exact structure: 128x64 tile, BK=64, single-
// buffered 24 KB LDS, XOR-swizzled global_load_lds, 2 barriers/K-step.
// ---------------------------------------------------------------------------
__global__ __launch_bounds__(256) void gemm_qk_mfma(
    const u16* __restrict__ A, const u16* __restrict__ W,
    const float* __restrict__ bq, const float* __restrict__ bk,
    u16* __restrict__ QKb)
{
    __shared__ __align__(16) u16 As[128 * 64];   // 16 KB
    __shared__ __align__(16) u16 Bs[64 * 64];    // 8 KB
    const int t = threadIdx.x;

    const int m0 = (blockIdx.x & 31) * 128;
    const int n0 = (blockIdx.x >> 5) * 64;             // 0..960
    const int sel = n0 >> 9;                           // 0:Q 1:K
    const float* bias = ((sel == 0) ? bq : bk) + (n0 & 511);

    const int wave = t >> 6, lane = t & 63;
    const int wm   = wave >> 1, wn = wave & 1;
    const int qd   = lane >> 4, lr = lane & 15;

    const int sr8 = lane >> 3;                 // row-in-8 for staging
    const int sg  = (lane & 7) ^ sr8;          // swizzled global granule
    const int soff = sg * 8;                   // global k offset (elems)

    f32x4 acc[4][2] = {};

    const u16* Ag = A + (size_t)m0 * EMBED;
    const u16* Wg = W + (size_t)n0 * EMBED;

    u16* Adst = As + (size_t)(wave * 8) * 64;
    u16* Bdst = Bs + (size_t)(wave * 8) * 64;
    const u16* Asrc = Ag + (size_t)(wave * 8 + sr8) * EMBED + soff;
    const u16* Bsrc = Wg + (size_t)(wave * 8 + sr8) * EMBED + soff;

    for (int kc = 0; kc < EMBED; kc += 64) {
#pragma unroll
        for (int j = 0; j < 4; ++j)
            __builtin_amdgcn_global_load_lds(
                (const __attribute__((address_space(1))) void*)(Asrc + kc + (size_t)j * 32 * EMBED),
                (__attribute__((address_space(3))) void*)(Adst + j * 32 * 64), 16, 0, 0);
#pragma unroll
        for (int j = 0; j < 2; ++j)
            __builtin_amdgcn_global_load_lds(
                (const __attribute__((address_space(1))) void*)(Bsrc + kc + (size_t)j * 32 * EMBED),
                (__attribute__((address_space(3))) void*)(Bdst + j * 32 * 64), 16, 0, 0);
        __syncthreads();

#pragma unroll
        for (int kk = 0; kk < 2; ++kk) {
            const int gr = ((kk * 4 + qd) ^ (lr & 7)) * 8;
            bf16x8 af[4], bfr[2];
#pragma unroll
            for (int i = 0; i < 4; ++i)
                af[i]  = *(const bf16x8*)&As[(wm * 64 + i * 16 + lr) * 64 + gr];
#pragma unroll
            for (int i = 0; i < 2; ++i)
                bfr[i] = *(const bf16x8*)&Bs[(wn * 32 + i * 16 + lr) * 64 + gr];
#pragma unroll
            for (int mi = 0; mi < 4; ++mi)
#pragma unroll
                for (int ni = 0; ni < 2; ++ni)
                    acc[mi][ni] = __builtin_amdgcn_mfma_f32_16x16x32_bf16(
                        af[mi], bfr[ni], acc[mi][ni], 0, 0, 0);
        }
        __syncthreads();
    }

    // C/D layout: col=lane&15, row=(lane>>4)*4+reg
#pragma unroll
    for (int ni = 0; ni < 2; ++ni) {
        const int cl = wn * 32 + ni * 16 + lr;
        const float bb = bias[cl];
#pragma unroll
        for (int mi = 0; mi < 4; ++mi)
#pragma unroll
            for (int e = 0; e < 4; ++e) {
                const int row = m0 + wm * 64 + mi * 16 + qd * 4 + e;
                QKb[(size_t)row * 1024 + n0 + cl] = f2bf(acc[mi][ni][e] + bb);
            }
    }
}

// ---------------------------------------------------------------------------
// Fused attention + K=32 output GEMM. 256 blocks x 16 rows (R0 proven).
// ---------------------------------------------------------------------------
__global__ __launch_bounds__(256) void attn_out_kernel(
    const u16* __restrict__ QKb, const float* __restrict__ WT,
    const float* __restrict__ bo, float* __restrict__ out)
{
    __shared__ float E[16][32];
    const int r0   = blockIdx.x * 16;
    const int b    = r0 >> 11;
    const int wave = threadIdx.x >> 6, lane = threadIdx.x & 63;
    const int d0   = lane * 8;

#pragma unroll
    for (int i = 0; i < 4; ++i) {
        const int rl = wave * 4 + i;
        const int r  = r0 + rl;
        const int sr = r & (NSEQ - 1);
        const u16* Qr = QKb + (size_t)r * 1024 + d0;
        const u16* Kr = QKb + (size_t)r * 1024 + 512 + d0;

        ushort8 qv = *(const ushort8*)Qr;
        ushort8 kv = *(const ushort8*)Kr;
        float q[8], k[8];
#pragma unroll
        for (int z = 0; z < 8; ++z) { q[z] = bf2f(qv[z]); k[z] = bf2f(kv[z]); }

        float s1 = 0.f;
#pragma unroll
        for (int z = 0; z < 8; ++z) s1 = fmaf(q[z], k[z], s1);

        float s0 = 0.f, s2 = 0.f;
        if (sr > 0) {
            ushort8 pv = *(const ushort8*)(Kr - 1024);
#pragma unroll
            for (int z = 0; z < 8; ++z) s0 = fmaf(q[z], bf2f(pv[z]), s0);
        }
        if (sr < NSEQ - 1) {
            ushort8 nv = *(const ushort8*)(Kr + 1024);
#pragma unroll
            for (int z = 0; z < 8; ++z) s2 = fmaf(q[z], bf2f(nv[z]), s2);
        }
#pragma unroll
        for (int off = 1; off <= 4; off <<= 1) {
            s0 += __shfl_xor(s0, off);
            s1 += __shfl_xor(s1, off);
            s2 += __shfl_xor(s2, off);
        }
        const float m  = fmaxf(fmaxf(s0, s1), fmaxf(s2, 0.f));
        const float e0 = __expf(s0 - m);
        const float e1 = __expf(s1 - m);
        const float e2 = __expf(s2 - m);
        const float eb = __expf(-m);
        const float rd = 1.f / (e0 + e1 + e2 + (float)(NSEQ - 3) * eb);
        const int h = lane >> 3, jj = lane & 7;
        const float coef = (jj == 0) ? e0 : (jj == 1) ? e1 : (jj == 2) ? e2 : eb;
        if (jj < 4) E[rl][h * 4 + jj] = coef * rd;
    }
    __syncthreads();

    const int j0 = threadIdx.x * 2;
    const float* WTb = WT + (size_t)b * 512 * 32;
    float w0[32], w1[32];
#pragma unroll
    for (int s = 0; s < 32; ++s) {
        w0[s] = WTb[(size_t)j0 * 32 + s];
        w1[s] = WTb[(size_t)(j0 + 1) * 32 + s];
    }
    const float b0 = bo[j0], b1 = bo[j0 + 1];
#pragma unroll
    for (int rl = 0; rl < 16; ++rl) {
        float a0 = b0, a1 = b1;
#pragma unroll
        for (int s = 0; s < 32; ++s) {
            const float e = E[rl][s];
            a0 = fmaf(e, w0[s], a0);
            a1 = fmaf(e, w1[s], a1);
        }
        *(float2*)(out + (size_t)(r0 + rl) * EMBED + j0) = make_float2(a0, a1);
    }
}

extern "C" void kernel_launch(void* const* d_in, const int* in_sizes, int n_in,
                              void* d_out, int out_size, void* d_ws, size_t ws_size,
                              hipStream_t stream)
{
    const float* x  = (const float*)d_in[0];
    const float* Wq = (const float*)d_in[1];
    const float* bq = (const float*)d_in[2];
    const float* Wk = (const float*)d_in[3];
    const float* bk = (const float*)d_in[4];
    const float* Wv = (const float*)d_in[5];
    const float* bv = (const float*)d_in[6];
    const float* Wo = (const float*)d_in[7];
    const float* bo = (const float*)d_in[8];
    float* out = (float*)d_out;

    u16*   QKb      = (u16*)d_ws;                      // 4096*1024 u16 (Q|K bf16)
    u16*   xb       = QKb + (size_t)NROWS * 1024;      // 4096*512 bf16
    u16*   Wcat     = xb + XELEMS;                     // 1024*512 bf16 (Wq|Wk)
    float* xcs_part = (float*)(Wcat + WQKELEMS);       // 2*32*512 f32
    float* WT       = xcs_part + 2 * 32 * 512;         // 2*512*32 f32

    prep_kernel<<<1344, 256, 0, stream>>>(x, Wq, Wk, xb, Wcat, xcs_part);
    vsmall_kernel<<<32, 256, 0, stream>>>(xb, xcs_part, bv, Wv, Wo, WT);
    gemm_qk_mfma<<<512, 256, 0, stream>>>(xb, Wcat, bq, bk, QKb);
    attn_out_kernel<<<256, 256, 0, stream>>>(QKb, WT, bo, out);
}

// Round 7
// 105.769 us; speedup vs baseline: 1.1501x; 1.1501x over previous
//
#include <hip/hip_runtime.h>
#include <hip/hip_bf16.h>

#define EMBED 512
#define NSEQ 2048
#define NROWS 4096

typedef unsigned short u16;
typedef __bf16 bf16x8 __attribute__((ext_vector_type(8)));
typedef float f32x4 __attribute__((ext_vector_type(4)));
typedef unsigned short ushort8 __attribute__((ext_vector_type(8)));

__device__ __forceinline__ u16 f2bf(float f) {
    unsigned u = __float_as_uint(f);
    unsigned r = (u + 0x7FFFu + ((u >> 16) & 1u)) >> 16;
    return (u16)r;
}
__device__ __forceinline__ float bf2f(u16 v) {
    return __uint_as_float((unsigned)v << 16);
}

#define XELEMS    (NROWS * EMBED)     // 2097152
#define WCATELEMS (1536 * EMBED)      // 786432
#define NCONVB    1408                // (XELEMS+WCATELEMS)/8/256

// ---------------------------------------------------------------------------
// prep: x -> bf16, Wq|Wk|Wv -> Wcat bf16.
// ---------------------------------------------------------------------------
__global__ __launch_bounds__(256) void prep_kernel(
    const float* __restrict__ x,
    const float* __restrict__ Wq, const float* __restrict__ Wk,
    const float* __restrict__ Wv,
    u16* __restrict__ xb, u16* __restrict__ Wcat)
{
    const long long e0 = (long long)(blockIdx.x * 256 + threadIdx.x) * 8;
    const float* src;
    u16* dst;
    if (e0 < XELEMS) {
        src = x + e0; dst = xb + e0;
    } else {
        const long long j = e0 - XELEMS;
        const int row = (int)(j >> 9);
        const int col = (int)(j & 511);
        const int sel = row >> 9;            // 0:Wq 1:Wk 2:Wv
        const int r   = row & 511;
        const float* W = (sel == 0) ? Wq : (sel == 1) ? Wk : Wv;
        src = W + (size_t)r * EMBED + col; dst = Wcat + j;
    }
    float4 a = *(const float4*)(src);
    float4 b = *(const float4*)(src + 4);
    union { u16 u[8]; uint4 v; } p;
    p.u[0] = f2bf(a.x); p.u[1] = f2bf(a.y); p.u[2] = f2bf(a.z); p.u[3] = f2bf(a.w);
    p.u[4] = f2bf(b.x); p.u[5] = f2bf(b.y); p.u[6] = f2bf(b.z); p.u[7] = f2bf(b.w);
    *(uint4*)(dst) = p.v;
}

// ---------------------------------------------------------------------------
// QKV GEMM: 768 blocks, one 128x64 tile each. BK=64, XOR-swizzled LDS
// (2-way bank aliasing on fragment reads = free).
// Q,K tiles (sel<2): store bf16 into QKb[row][col] (col 0..1023).
// V tiles (sel==2): store rows 0..2 per batch into Vhead (fp32, +bias) and
// write per-(col, mtile, wm) pre-bias column sums into write-once vpart slots.
// ---------------------------------------------------------------------------
__global__ __launch_bounds__(256) void gemm_qkv_mfma(
    const u16* __restrict__ A, const u16* __restrict__ W,
    const float* __restrict__ bq, const float* __restrict__ bk,
    const float* __restrict__ bvv,
    u16* __restrict__ QKb, float* __restrict__ Vhead,
    float* __restrict__ vpart)
{
    __shared__ __align__(16) u16 As[128 * 64];   // 16 KB
    __shared__ __align__(16) u16 Bs[64 * 64];    // 8 KB

    const int m0 = (blockIdx.x & 31) * 128;
    const int n0 = (blockIdx.x >> 5) * 64;             // 0..1472
    const int sel = n0 >> 9;
    const float* bias = ((sel == 0) ? bq : (sel == 1) ? bk : bvv) + (n0 & 511);

    const int t    = threadIdx.x;
    const int wave = t >> 6, lane = t & 63;
    const int wm   = wave >> 1, wn = wave & 1;
    const int qd   = lane >> 4, lr = lane & 15;

    const int sr8 = lane >> 3;                 // row-in-8 for staging
    const int sg  = (lane & 7) ^ sr8;          // swizzled global granule
    const int soff = sg * 8;                   // global k offset (elems)

    f32x4 acc[4][2] = {};

    const u16* Ag = A + (size_t)m0 * EMBED;
    const u16* Wg = W + (size_t)n0 * EMBED;

    u16* Adst = As + (size_t)(wave * 8) * 64;
    u16* Bdst = Bs + (size_t)(wave * 8) * 64;
    const u16* Asrc = Ag + (size_t)(wave * 8 + sr8) * EMBED + soff;
    const u16* Bsrc = Wg + (size_t)(wave * 8 + sr8) * EMBED + soff;

    for (int kc = 0; kc < EMBED; kc += 64) {
#pragma unroll
        for (int j = 0; j < 4; ++j)
            __builtin_amdgcn_global_load_lds(
                (const __attribute__((address_space(1))) void*)(Asrc + kc + (size_t)j * 32 * EMBED),
                (__attribute__((address_space(3))) void*)(Adst + j * 32 * 64), 16, 0, 0);
#pragma unroll
        for (int j = 0; j < 2; ++j)
            __builtin_amdgcn_global_load_lds(
                (const __attribute__((address_space(1))) void*)(Bsrc + kc + (size_t)j * 32 * EMBED),
                (__attribute__((address_space(3))) void*)(Bdst + j * 32 * 64), 16, 0, 0);
        __syncthreads();

#pragma unroll
        for (int kk = 0; kk < 2; ++kk) {
            const int gr = ((kk * 4 + qd) ^ (lr & 7)) * 8;
            bf16x8 af[4], bfr[2];
#pragma unroll
            for (int i = 0; i < 4; ++i)
                af[i]  = *(const bf16x8*)&As[(wm * 64 + i * 16 + lr) * 64 + gr];
#pragma unroll
            for (int i = 0; i < 2; ++i)
                bfr[i] = *(const bf16x8*)&Bs[(wn * 32 + i * 16 + lr) * 64 + gr];
#pragma unroll
            for (int mi = 0; mi < 4; ++mi)
#pragma unroll
                for (int ni = 0; ni < 2; ++ni)
                    acc[mi][ni] = __builtin_amdgcn_mfma_f32_16x16x32_bf16(
                        af[mi], bfr[ni], acc[mi][ni], 0, 0, 0);
        }
        __syncthreads();
    }

    // C/D layout: col=lane&15, row=(lane>>4)*4+reg
    if (sel < 2) {
#pragma unroll
        for (int ni = 0; ni < 2; ++ni) {
            const int cl = wn * 32 + ni * 16 + lr;
            const float bb = bias[cl];
#pragma unroll
            for (int mi = 0; mi < 4; ++mi)
#pragma unroll
                for (int e = 0; e < 4; ++e) {
                    const int row = m0 + wm * 64 + mi * 16 + qd * 4 + e;
                    QKb[(size_t)row * 1024 + n0 + cl] = f2bf(acc[mi][ni][e] + bb);
                }
        }
    } else {
        const int batch = m0 >> 11;          // tile never crosses batch
        const int mtb   = (m0 >> 7) & 15;    // m-tile within batch
#pragma unroll
        for (int ni = 0; ni < 2; ++ni) {
            const int cl  = wn * 32 + ni * 16 + lr;
            const int col = (n0 - 1024) + cl;            // 0..511
            const float bb = bias[cl];
            float s = 0.f;
#pragma unroll
            for (int mi = 0; mi < 4; ++mi)
#pragma unroll
                for (int e = 0; e < 4; ++e) {
                    const int row = m0 + wm * 64 + mi * 16 + qd * 4 + e;
                    s += acc[mi][ni][e];
                    if ((row & (NSEQ - 1)) < 3)
                        Vhead[(size_t)batch * 1536 + (row & (NSEQ - 1)) * 512 + col]
                            = acc[mi][ni][e] + bb;
                }
            s += __shfl_xor(s, 16);
            s += __shfl_xor(s, 32);
            if (qd == 0)   // one slot per (batch,col,mtb,wm): written exactly once
                vpart[((size_t)batch * 512 + col) * 32 + mtb * 2 + wm] = s;
        }
    }
}

// ---------------------------------------------------------------------------
// Wsmall: WT[b][j][s] (s=4h+t) = sum_{c in head h} Vsm[b][t][c] * Wo[j][c]
// Vsm t=0,1,2 -> Vhead rows (biased); t=3 -> tail = sum32(vpart) + 2048*bv
// - (v0+v1+v2). Grid 128 blocks (2 batches x 64 j-groups of 8).
// ---------------------------------------------------------------------------
__global__ __launch_bounds__(256) void wsmall_kernel(
    const float* __restrict__ Vhead, const float* __restrict__ vpart,
    const float* __restrict__ bv,
    const float* __restrict__ Wo, float* __restrict__ WT)
{
    __shared__ float Vsm[4][512];
    const int b  = blockIdx.x >> 6;
    const int jb = blockIdx.x & 63;
    const int t  = threadIdx.x;

    for (int idx = t; idx < 512; idx += 256) {
        const float v0 = Vhead[(size_t)b * 1536 + idx];
        const float v1 = Vhead[(size_t)b * 1536 + 512 + idx];
        const float v2 = Vhead[(size_t)b * 1536 + 1024 + idx];
        float sum = 0.f;
        const float* vp = vpart + ((size_t)b * 512 + idx) * 32;
#pragma unroll
        for (int s = 0; s < 32; ++s) sum += vp[s];
        Vsm[0][idx] = v0; Vsm[1][idx] = v1; Vsm[2][idx] = v2;
        Vsm[3][idx] = sum + (float)NSEQ * bv[idx] - (v0 + v1 + v2);
    }
    __syncthreads();

    const int j  = jb * 8 + (t >> 5);
    const int s  = t & 31;
    const int h  = s >> 2, tt = s & 3;
    const float* Wor = Wo + (size_t)j * EMBED + h * 64;
    const float* vr  = &Vsm[tt][h * 64];
    float acc = 0.f;
#pragma unroll
    for (int c = 0; c < 64; ++c) {
        const int cc = (c + 2 * s) & 63;    // rotate to spread LDS banks
        acc = fmaf(vr[cc], Wor[cc], acc);
    }
    WT[((size_t)b * 512 + j) * 32 + s] = acc;
}

// ---------------------------------------------------------------------------
// Fused attention + K=32 output GEMM. Grid 256 blocks x 16 rows.
// Q,K read as bf16 (16B/lane loads), dots in fp32.
// ---------------------------------------------------------------------------
__global__ __launch_bounds__(256) void attn_out_kernel(
    const u16* __restrict__ QKb, const float* __restrict__ WT,
    const float* __restrict__ bo, float* __restrict__ out)
{
    __shared__ float E[16][32];
    const int r0   = blockIdx.x * 16;
    const int b    = r0 >> 11;
    const int wave = threadIdx.x >> 6, lane = threadIdx.x & 63;
    const int d0   = lane * 8;

#pragma unroll
    for (int i = 0; i < 4; ++i) {
        const int rl = wave * 4 + i;
        const int r  = r0 + rl;
        const int sr = r & (NSEQ - 1);
        const u16* Qr = QKb + (size_t)r * 1024 + d0;
        const u16* Kr = QKb + (size_t)r * 1024 + 512 + d0;

        ushort8 qv = *(const ushort8*)Qr;
        ushort8 kv = *(const ushort8*)Kr;
        float q[8], k[8];
#pragma unroll
        for (int z = 0; z < 8; ++z) { q[z] = bf2f(qv[z]); k[z] = bf2f(kv[z]); }

        float s1 = 0.f;
#pragma unroll
        for (int z = 0; z < 8; ++z) s1 = fmaf(q[z], k[z], s1);

        float s0 = 0.f, s2 = 0.f;
        if (sr > 0) {
            ushort8 pv = *(const ushort8*)(Kr - 1024);
#pragma unroll
            for (int z = 0; z < 8; ++z) s0 = fmaf(q[z], bf2f(pv[z]), s0);
        }
        if (sr < NSEQ - 1) {
            ushort8 nv = *(const ushort8*)(Kr + 1024);
#pragma unroll
            for (int z = 0; z < 8; ++z) s2 = fmaf(q[z], bf2f(nv[z]), s2);
        }
#pragma unroll
        for (int off = 1; off <= 4; off <<= 1) {
            s0 += __shfl_xor(s0, off);
            s1 += __shfl_xor(s1, off);
            s2 += __shfl_xor(s2, off);
        }
        const float m  = fmaxf(fmaxf(s0, s1), fmaxf(s2, 0.f));
        const float e0 = __expf(s0 - m);
        const float e1 = __expf(s1 - m);
        const float e2 = __expf(s2 - m);
        const float eb = __expf(-m);
        const float rd = 1.f / (e0 + e1 + e2 + (float)(NSEQ - 3) * eb);
        const int h = lane >> 3, jj = lane & 7;
        const float coef = (jj == 0) ? e0 : (jj == 1) ? e1 : (jj == 2) ? e2 : eb;
        if (jj < 4) E[rl][h * 4 + jj] = coef * rd;
    }
    __syncthreads();

    const int j0 = threadIdx.x * 2;
    const float* WTb = WT + (size_t)b * 512 * 32;
    float w0[32], w1[32];
#pragma unroll
    for (int s = 0; s < 32; ++s) {
        w0[s] = WTb[(size_t)j0 * 32 + s];
        w1[s] = WTb[(size_t)(j0 + 1) * 32 + s];
    }
    const float b0 = bo[j0], b1 = bo[j0 + 1];
#pragma unroll
    for (int rl = 0; rl < 16; ++rl) {
        float a0 = b0, a1 = b1;
#pragma unroll
        for (int s = 0; s < 32; ++s) {
            const float e = E[rl][s];
            a0 = fmaf(e, w0[s], a0);
            a1 = fmaf(e, w1[s], a1);
        }
        float2 o = make_float2(a0, a1);
        *(float2*)(out + (size_t)(r0 + rl) * EMBED + j0) = o;
    }
}

extern "C" void kernel_launch(void* const* d_in, const int* in_sizes, int n_in,
                              void* d_out, int out_size, void* d_ws, size_t ws_size,
                              hipStream_t stream)
{
    const float* x  = (const float*)d_in[0];
    const float* Wq = (const float*)d_in[1];
    const float* bq = (const float*)d_in[2];
    const float* Wk = (const float*)d_in[3];
    const float* bk = (const float*)d_in[4];
    const float* Wv = (const float*)d_in[5];
    const float* bv = (const float*)d_in[6];
    const float* Wo = (const float*)d_in[7];
    const float* bo = (const float*)d_in[8];
    float* out = (float*)d_out;

    u16*   QKb   = (u16*)d_ws;                     // 4096*1024 u16 (Q|K bf16)
    u16*   xb    = QKb + (size_t)NROWS * 1024;     // 2097152 bf16
    u16*   Wcat  = xb + XELEMS;                    // 786432 bf16
    float* Vhead = (float*)(Wcat + WCATELEMS);     // 2*3*512 f32
    float* vpart = Vhead + 2 * 3 * 512;            // 2*512*32 f32 (write-once)
    float* WT    = vpart + 2 * 512 * 32;           // 2*512*32 f32

    prep_kernel<<<NCONVB, 256, 0, stream>>>(x, Wq, Wk, Wv, xb, Wcat);
    gemm_qkv_mfma<<<768, 256, 0, stream>>>(xb, Wcat, bq, bk, bv, QKb, Vhead, vpart);
    wsmall_kernel<<<128, 256, 0, stream>>>(Vhead, vpart, bv, Wo, WT);
    attn_out_kernel<<<256, 256, 0, stream>>>(QKb, WT, bo, out);
}